// Round 12
// baseline (323.336 us; speedup 1.0000x reference)
//
#include <hip/hip_runtime.h>

#define NND 50000
#define NED 800000
#define NF  128
#define NH  64
#define BN_EPS 1e-5
#define NCOPY 8    // stats slot-copies (f32)
#define SCB  256   // scan chunk
#define NSB  ((NND + SCB - 1) / SCB)   // 196 scan blocks
#define XNODES (NND / 8)               // 6250 nodes per XCD slice
#define FCH  196                       // edge chunks (1024 int4 each) per XCD pass

// ---- workspace byte offsets (16B aligned) ----
#define WS_HB     0                          // bf16[NND*64]  (h, gather source)   6,400,000 B
#define WS_AGG    6400000                    // bf16[NND*64]  (agg, MLP input)     6,400,000 B
#define WS_STATS  12800000                   // float[4][NCOPY*128] = 16 KB (4 stages, memset each call)
#define WS_DEG    (WS_STATS + 4*NCOPY*128*4) // int[NND]  (memset'd with stats)
#define WS_OFFS   (WS_DEG + NND*4)           // int[NND+4]
#define WS_CUR    (WS_OFFS + (NND+4)*4)      // int[NND]
#define WS_PARTS  (WS_CUR + NND*4)           // int[256]
#define WS_ESRC   (WS_PARTS + 256*4)         // int[NED]

typedef int int4v __attribute__((ext_vector_type(4)));

// ---- bf16 helpers (storage-only; all math in f32) ----
__device__ __forceinline__ unsigned bfrn(float x) {          // f32 -> bf16 (RTN-even)
    unsigned u = __float_as_uint(x);
    return (u + 0x7fffu + ((u >> 16) & 1u)) >> 16;
}
__device__ __forceinline__ unsigned pk(float lo, float hi) { // 2x f32 -> packed bf16x2
    return bfrn(lo) | (bfrn(hi) << 16);
}
__device__ __forceinline__ void upadd(unsigned u, float& lo, float& hi) {
    lo += __uint_as_float(u << 16);
    hi += __uint_as_float(u & 0xffff0000u);
}
__device__ __forceinline__ float ulo(unsigned u) { return __uint_as_float(u << 16); }
__device__ __forceinline__ float uhi(unsigned u) { return __uint_as_float(u & 0xffff0000u); }

// derive BN scale/shift for column c from f32 slot-copy stats
__device__ __forceinline__ void bn_derive(const float* __restrict__ st, int c,
                                          const float* __restrict__ g,
                                          const float* __restrict__ b,
                                          float& sc, float& sh) {
    float sum = 0.f, ssq = 0.f;
#pragma unroll
    for (int cp = 0; cp < NCOPY; ++cp) {
        sum += st[cp * 128 + c];
        ssq += st[cp * 128 + 64 + c];
    }
    double mu  = (double)sum / (double)NND;
    double var = (double)ssq / (double)NND - mu * mu;
    if (var < 0.0) var = 0.0;
    double rs = 1.0 / sqrt(var + BN_EPS);
    double scd = (double)g[c] * rs;
    sc = (float)scd;
    sh = (float)((double)b[c] - mu * scd);
}

// ---------------- CSR build (XCD-partitioned; edge streams NONTEMPORAL) ----------------
// blockIdx%8 -> XCD; each XCD owns dst range [x*XNODES,(x+1)*XNODES). nt loads keep
// the 8x-replayed 3.2MB dst/src streams OUT of L2 so deg/cur/esrc lines stay resident
// (R11: fill WRITE_SIZE 31.5MB for ~4MB of data = partial-line evictions by the stream).
__global__ __launch_bounds__(256) void k_deg(const int* __restrict__ dst,
                                             int* __restrict__ deg) {
    int xcd = blockIdx.x & 7;
    int chunk = blockIdx.x >> 3;
    int lo = xcd * XNODES;
    const int4v* d4 = (const int4v*)dst;
#pragma unroll
    for (int r = 0; r < 4; ++r) {
        int i = chunk * 1024 + r * 256 + threadIdx.x;
        if (i < NED / 4) {
            int4v d = __builtin_nontemporal_load(d4 + i);
            if ((unsigned)(d.x - lo) < XNODES) atomicAdd(&deg[d.x], 1);
            if ((unsigned)(d.y - lo) < XNODES) atomicAdd(&deg[d.y], 1);
            if ((unsigned)(d.z - lo) < XNODES) atomicAdd(&deg[d.z], 1);
            if ((unsigned)(d.w - lo) < XNODES) atomicAdd(&deg[d.w], 1);
        }
    }
}

__global__ __launch_bounds__(256) void k_fill(const int* __restrict__ src,
                                              const int* __restrict__ dst,
                                              int* __restrict__ cur,
                                              int* __restrict__ esrc) {
    int xcd = blockIdx.x & 7;
    int chunk = blockIdx.x >> 3;
    int lo = xcd * XNODES;
    const int4v* d4 = (const int4v*)dst;
    const int4v* s4 = (const int4v*)src;
#pragma unroll
    for (int r = 0; r < 4; ++r) {
        int i = chunk * 1024 + r * 256 + threadIdx.x;
        if (i < NED / 4) {
            int4v d = __builtin_nontemporal_load(d4 + i);
            int4v s = __builtin_nontemporal_load(s4 + i);
            if ((unsigned)(d.x - lo) < XNODES) esrc[atomicAdd(&cur[d.x], 1)] = s.x;
            if ((unsigned)(d.y - lo) < XNODES) esrc[atomicAdd(&cur[d.y], 1)] = s.y;
            if ((unsigned)(d.z - lo) < XNODES) esrc[atomicAdd(&cur[d.z], 1)] = s.z;
            if ((unsigned)(d.w - lo) < XNODES) esrc[atomicAdd(&cur[d.w], 1)] = s.w;
        }
    }
}

__global__ __launch_bounds__(SCB) void k_part(const int* __restrict__ deg,
                                              int* __restrict__ offs,
                                              int* __restrict__ parts) {
    __shared__ int sd[SCB];
    int t = threadIdx.x;
    int i = blockIdx.x * SCB + t;
    int v = (i < NND) ? deg[i] : 0;
    sd[t] = v;
    __syncthreads();
#pragma unroll
    for (int off = 1; off < SCB; off <<= 1) {
        int u = (t >= off) ? sd[t - off] : 0;
        __syncthreads();
        sd[t] += u;
        __syncthreads();
    }
    if (i < NND) offs[i] = sd[t] - v;
    if (t == SCB - 1) parts[blockIdx.x] = sd[t];
}

__global__ __launch_bounds__(256) void k_scan2(int* __restrict__ parts) {
    __shared__ int sd[256];
    int t = threadIdx.x;
    int v = (t < NSB) ? parts[t] : 0;
    sd[t] = v;
    __syncthreads();
#pragma unroll
    for (int off = 1; off < 256; off <<= 1) {
        int u = (t >= off) ? sd[t - off] : 0;
        __syncthreads();
        sd[t] += u;
        __syncthreads();
    }
    if (t < NSB) parts[t] = sd[t] - v;
}

__global__ __launch_bounds__(256) void k_apply(int* __restrict__ offs,
                                               const int* __restrict__ parts,
                                               int* __restrict__ cur) {
    int i = blockIdx.x * 256 + threadIdx.x;
    if (i < NND) {
        int o = offs[i] + parts[i >> 8];
        offs[i] = o;
        cur[i] = o;
    }
    if (i == NND) offs[NND] = NED;
}

// ---------------- input transform: col-split, bf16 W in LDS (33.8KB -> 4 blocks/CU) ----------------
__global__ __launch_bounds__(128) void k_transform(const float* __restrict__ x,
                                                   const float* __restrict__ Wt,
                                                   const float* __restrict__ bt,
                                                   unsigned* __restrict__ hB,
                                                   float* __restrict__ stats) {
    __shared__ __align__(16) unsigned Wlu[NF * NH / 2]; // 16 KB, bf16-packed
    __shared__ __align__(16) float sT[64 * 68];         // 17.4 KB
    int tid  = threadIdx.x;
    int wave = tid >> 6, lane = tid & 63;
    int ti = lane & 7, tj = lane >> 3;
    int tile = blockIdx.x;                              // 0..781
    int base = tile * 64;
    const float4* x4 = (const float4*)x;

    // stage W as bf16 pairs: 2048 float4 -> 2048 uint2
#pragma unroll
    for (int r = 0; r < 16; ++r) {
        int i4 = r * 128 + tid;
        float4 w = ((const float4*)Wt)[i4];
        uint2 wp; wp.x = pk(w.x, w.y); wp.y = pk(w.z, w.w);
        ((uint2*)Wlu)[i4] = wp;
    }

    float acc[8][4];
#pragma unroll
    for (int i = 0; i < 8; ++i)
#pragma unroll
        for (int j = 0; j < 4; ++j) acc[i][j] = 0.f;

    int cw = wave * 32 + tj * 4;                        // this lane's 4 output cols

    for (int ch = 0; ch < 2; ++ch) {
        __syncthreads();
        // T14 split: issue ALL chunk loads into regs, then LDS stores
        float4 pf[8];
#pragma unroll
        for (int s = 0; s < 8; ++s) {
            int flat = s * 128 + tid;
            int nl = flat >> 4, q = flat & 15;
            pf[s] = make_float4(0.f, 0.f, 0.f, 0.f);
            if (base + nl < NND) pf[s] = x4[(size_t)(base + nl) * 32 + ch * 16 + q];
        }
#pragma unroll
        for (int s = 0; s < 8; ++s) {
            int flat = s * 128 + tid;
            int nl = flat >> 4, q = flat & 15;
            sT[(q * 4 + 0) * 68 + nl] = pf[s].x;
            sT[(q * 4 + 1) * 68 + nl] = pf[s].y;
            sT[(q * 4 + 2) * 68 + nl] = pf[s].z;
            sT[(q * 4 + 3) * 68 + nl] = pf[s].w;
        }
        __syncthreads();
#pragma unroll 4
        for (int k = 0; k < 64; ++k) {
            const float* ap = &sT[k * 68 + ti * 8];
            float4 alo = *(const float4*)ap;
            float4 ahi = *(const float4*)(ap + 4);
            uint2 wu = *(const uint2*)&Wlu[(ch * 64 + k) * 32 + (cw >> 1)];
            float a8[8] = {alo.x, alo.y, alo.z, alo.w, ahi.x, ahi.y, ahi.z, ahi.w};
            float w4[4] = {ulo(wu.x), uhi(wu.x), ulo(wu.y), uhi(wu.y)};
#pragma unroll
            for (int i = 0; i < 8; ++i)
#pragma unroll
                for (int j = 0; j < 4; ++j) acc[i][j] += a8[i] * w4[j];
        }
    }

    float4 bv = *(const float4*)&bt[cw];
    float bj[4] = {bv.x, bv.y, bv.z, bv.w};

    float s4[4] = {0.f, 0.f, 0.f, 0.f}, q4[4] = {0.f, 0.f, 0.f, 0.f};
    uint2* hB2 = (uint2*)hB;
#pragma unroll
    for (int i = 0; i < 8; ++i) {
        int n = base + ti * 8 + i;
        if (n < NND) {
            float o[4];
#pragma unroll
            for (int j = 0; j < 4; ++j) {
                o[j] = acc[i][j] + bj[j];
                s4[j] += o[j];
                q4[j] += o[j] * o[j];
            }
            uint2 ov; ov.x = pk(o[0], o[1]); ov.y = pk(o[2], o[3]);
            hB2[(size_t)n * 16 + wave * 8 + tj] = ov;
        }
    }
#pragma unroll
    for (int m = 1; m < 8; m <<= 1) {
#pragma unroll
        for (int j = 0; j < 4; ++j) {
            s4[j] += __shfl_xor(s4[j], m);
            q4[j] += __shfl_xor(q4[j], m);
        }
    }
    if (ti == 0) {
        int slot = (tile & (NCOPY - 1)) * 128;
#pragma unroll
        for (int j = 0; j < 4; ++j) {
            atomicAdd(&stats[slot + cw + j], s4[j]);
            atomicAdd(&stats[slot + 64 + cw + j], q4[j]);
        }
    }
}

// ---------------- aggregation: wave-per-node, bf16 rows; BN derived inline ----------------
__global__ __launch_bounds__(256) void k_agg(const uint4* __restrict__ hB4,
                                             uint4* __restrict__ aggB4,
                                             const float* __restrict__ stats,
                                             const float* __restrict__ g,
                                             const float* __restrict__ b,
                                             const int* __restrict__ offs,
                                             const int* __restrict__ esrc) {
    int tid  = threadIdx.x;
    int lane = tid & 63;
    int wv   = tid >> 6;
    int n = blockIdx.x * 4 + wv;
    int q = lane & 7;        // 16B sub-block within 128B row
    int r = lane >> 3;       // edge slot 0..7

    // per-lane BN derive for column `lane` (redundant across waves; L2-hot 4KB)
    float scl, shl;
    bn_derive(stats, lane, g, b, scl, shl);

    int e0 = offs[n], e1 = offs[n + 1];
    int deg = e1 - e0;

    float a[8];
#pragma unroll
    for (int i = 0; i < 8; ++i) a[i] = 0.f;

    if (r == 0) {
        uint4 u = hB4[(size_t)n * 8 + q];
        upadd(u.x, a[0], a[1]); upadd(u.y, a[2], a[3]);
        upadd(u.z, a[4], a[5]); upadd(u.w, a[6], a[7]);
    }

    for (int bb = e0; bb < e1; bb += 64) {
        int m = e1 - bb; if (m > 64) m = 64;
        int idx = (lane < m) ? esrc[bb + lane] : 0;
        int t = 0;
        for (; t + 32 <= m; t += 32) {
            int j0 = __shfl(idx, t + r);
            int j1 = __shfl(idx, t + 8 + r);
            int j2 = __shfl(idx, t + 16 + r);
            int j3 = __shfl(idx, t + 24 + r);
            uint4 u0 = hB4[(size_t)j0 * 8 + q];
            uint4 u1 = hB4[(size_t)j1 * 8 + q];
            uint4 u2 = hB4[(size_t)j2 * 8 + q];
            uint4 u3 = hB4[(size_t)j3 * 8 + q];
            upadd(u0.x, a[0], a[1]); upadd(u0.y, a[2], a[3]);
            upadd(u0.z, a[4], a[5]); upadd(u0.w, a[6], a[7]);
            upadd(u1.x, a[0], a[1]); upadd(u1.y, a[2], a[3]);
            upadd(u1.z, a[4], a[5]); upadd(u1.w, a[6], a[7]);
            upadd(u2.x, a[0], a[1]); upadd(u2.y, a[2], a[3]);
            upadd(u2.z, a[4], a[5]); upadd(u2.w, a[6], a[7]);
            upadd(u3.x, a[0], a[1]); upadd(u3.y, a[2], a[3]);
            upadd(u3.z, a[4], a[5]); upadd(u3.w, a[6], a[7]);
        }
        for (; t < m; t += 8) {
            int e = t + r;
            int j = __shfl(idx, e & 63);
            if (e < m) {
                uint4 u = hB4[(size_t)j * 8 + q];
                upadd(u.x, a[0], a[1]); upadd(u.y, a[2], a[3]);
                upadd(u.z, a[4], a[5]); upadd(u.w, a[6], a[7]);
            }
        }
    }

#pragma unroll
    for (int msk = 8; msk <= 32; msk <<= 1)
#pragma unroll
        for (int i = 0; i < 8; ++i) a[i] += __shfl_xor(a[i], msk);

    // gather the 8 (sc,sh) pairs for this lane's columns q*8..q*8+7
    float sc8[8], sh8[8];
#pragma unroll
    for (int j = 0; j < 8; ++j) {
        sc8[j] = __shfl(scl, q * 8 + j);
        sh8[j] = __shfl(shl, q * 8 + j);
    }

    if (r == 0) {
        float dn = (float)(deg + 1);
        float o[8];
#pragma unroll
        for (int j = 0; j < 8; ++j) o[j] = sc8[j] * a[j] + dn * sh8[j];
        uint4 ov;
        ov.x = pk(o[0], o[1]); ov.y = pk(o[2], o[3]);
        ov.z = pk(o[4], o[5]); ov.w = pk(o[6], o[7]);
        aggB4[(size_t)n * 8 + q] = ov;
    }
}

// ---------------- MLP: col-split 1-tile blocks (2 waves, acc 8x4), 2 GEMMs ----------------
__global__ __launch_bounds__(128) void k_mlp(const uint4* __restrict__ aggB4,
                                             float* __restrict__ outF,    // f32 out (last layer) or null
                                             unsigned* __restrict__ hBo,  // bf16 out or null
                                             float* __restrict__ stats,
                                             const float* __restrict__ W1,
                                             const float* __restrict__ W2) {
    __shared__ __align__(16) float W1l[NH * NH];  // 16 KB
    __shared__ __align__(16) float W2l[NH * NH];  // 16 KB
    __shared__ __align__(16) float sT[64 * 68];   // 17.4 KB (agg, then t1)
    int tid  = threadIdx.x;
    int wave = tid >> 6, lane = tid & 63;
    int ti = lane & 7, tj = lane >> 3;
    int tile = blockIdx.x;
    int base = tile * 64;
    int cw = wave * 32 + tj * 4;

#pragma unroll
    for (int r = 0; r < 8; ++r) {
        int i4 = r * 128 + tid;
        ((float4*)W1l)[i4] = ((const float4*)W1)[i4];
        ((float4*)W2l)[i4] = ((const float4*)W2)[i4];
    }
    // stage agg tile transposed (bf16 -> f32): 512 uint4 by 128 threads
#pragma unroll
    for (int s = 0; s < 4; ++s) {
        int i4 = s * 128 + tid;
        int nl = i4 >> 3, q = i4 & 7;
        uint4 u = make_uint4(0u, 0u, 0u, 0u);
        if (base + nl < NND) u = aggB4[(size_t)(base + nl) * 8 + q];
        sT[(q * 8 + 0) * 68 + nl] = ulo(u.x);
        sT[(q * 8 + 1) * 68 + nl] = uhi(u.x);
        sT[(q * 8 + 2) * 68 + nl] = ulo(u.y);
        sT[(q * 8 + 3) * 68 + nl] = uhi(u.y);
        sT[(q * 8 + 4) * 68 + nl] = ulo(u.z);
        sT[(q * 8 + 5) * 68 + nl] = uhi(u.z);
        sT[(q * 8 + 6) * 68 + nl] = ulo(u.w);
        sT[(q * 8 + 7) * 68 + nl] = uhi(u.w);
    }
    __syncthreads();

    // GEMM1: t1[:, cw..cw+3] = relu(agg @ W1)
    float a1[8][4];
#pragma unroll
    for (int i = 0; i < 8; ++i)
#pragma unroll
        for (int j = 0; j < 4; ++j) a1[i][j] = 0.f;
#pragma unroll 4
    for (int k = 0; k < 64; ++k) {
        const float* ap = &sT[k * 68 + ti * 8];
        float4 alo = *(const float4*)ap;
        float4 ahi = *(const float4*)(ap + 4);
        float4 wv  = *(const float4*)&W1l[k * NH + cw];
        float a8[8] = {alo.x, alo.y, alo.z, alo.w, ahi.x, ahi.y, ahi.z, ahi.w};
        float w4[4] = {wv.x, wv.y, wv.z, wv.w};
#pragma unroll
        for (int i = 0; i < 8; ++i)
#pragma unroll
            for (int j = 0; j < 4; ++j) a1[i][j] += a8[i] * w4[j];
    }
#pragma unroll
    for (int i = 0; i < 8; ++i)
#pragma unroll
        for (int j = 0; j < 4; ++j) a1[i][j] = fmaxf(a1[i][j], 0.f);

    __syncthreads();
#pragma unroll
    for (int j = 0; j < 4; ++j) {
        float* p = &sT[(cw + j) * 68 + ti * 8];
        float4 lo = {a1[0][j], a1[1][j], a1[2][j], a1[3][j]};
        float4 hi = {a1[4][j], a1[5][j], a1[6][j], a1[7][j]};
        *(float4*)p = lo;
        *(float4*)(p + 4) = hi;
    }
    __syncthreads();

    // GEMM2: out[:, cw..cw+3] = relu(t1 @ W2)
    float a2[8][4];
#pragma unroll
    for (int i = 0; i < 8; ++i)
#pragma unroll
        for (int j = 0; j < 4; ++j) a2[i][j] = 0.f;
#pragma unroll 4
    for (int k = 0; k < 64; ++k) {
        const float* ap = &sT[k * 68 + ti * 8];
        float4 alo = *(const float4*)ap;
        float4 ahi = *(const float4*)(ap + 4);
        float4 wv  = *(const float4*)&W2l[k * NH + cw];
        float a8[8] = {alo.x, alo.y, alo.z, alo.w, ahi.x, ahi.y, ahi.z, ahi.w};
        float w4[4] = {wv.x, wv.y, wv.z, wv.w};
#pragma unroll
        for (int i = 0; i < 8; ++i)
#pragma unroll
            for (int j = 0; j < 4; ++j) a2[i][j] += a8[i] * w4[j];
    }

    float s4[4] = {0.f, 0.f, 0.f, 0.f}, q4[4] = {0.f, 0.f, 0.f, 0.f};
    uint2* hBo2 = (uint2*)hBo;
#pragma unroll
    for (int i = 0; i < 8; ++i) {
        int n = base + ti * 8 + i;
        if (n < NND) {
            float o[4];
#pragma unroll
            for (int j = 0; j < 4; ++j) {
                o[j] = fmaxf(a2[i][j], 0.f);
                s4[j] += o[j];
                q4[j] += o[j] * o[j];
            }
            if (outF) *(float4*)&outF[(size_t)n * NH + cw] = *(float4*)&o[0];
            if (hBo) {
                uint2 ov; ov.x = pk(o[0], o[1]); ov.y = pk(o[2], o[3]);
                hBo2[(size_t)n * 16 + wave * 8 + tj] = ov;
            }
        }
    }
#pragma unroll
    for (int m = 1; m < 8; m <<= 1) {
#pragma unroll
        for (int j = 0; j < 4; ++j) {
            s4[j] += __shfl_xor(s4[j], m);
            q4[j] += __shfl_xor(q4[j], m);
        }
    }
    if (ti == 0) {
        int slot = (tile & (NCOPY - 1)) * 128;
#pragma unroll
        for (int j = 0; j < 4; ++j) {
            atomicAdd(&stats[slot + cw + j], s4[j]);
            atomicAdd(&stats[slot + 64 + cw + j], q4[j]);
        }
    }
}

// ---------------- final BN apply, in-place on f32 out; sc/sh derived per block ----------------
__global__ __launch_bounds__(256) void k_bnout(float* __restrict__ h,
                                               const float* __restrict__ stats,
                                               const float* __restrict__ g,
                                               const float* __restrict__ b) {
    __shared__ float sl[128];
    int tid = threadIdx.x;
    if (tid < 64) {
        float sc, sh;
        bn_derive(stats, tid, g, b, sc, sh);
        sl[tid]      = sc;
        sl[64 + tid] = sh;
    }
    __syncthreads();
    int i4 = blockIdx.x * 256 + tid;
    if (i4 < NND * NH / 4) {
        int cg = i4 & 15;
        float4 v   = ((float4*)h)[i4];
        float4 scv = *(float4*)&sl[cg * 4];
        float4 shv = *(float4*)&sl[64 + cg * 4];
        v.x = v.x * scv.x + shv.x;
        v.y = v.y * scv.y + shv.y;
        v.z = v.z * scv.z + shv.z;
        v.w = v.w * scv.w + shv.w;
        ((float4*)h)[i4] = v;
    }
}

extern "C" void kernel_launch(void* const* d_in, const int* in_sizes, int n_in,
                              void* d_out, int out_size, void* d_ws, size_t ws_size,
                              hipStream_t stream) {
    const float* x     = (const float*)d_in[0];
    const int*   ei    = (const int*)d_in[1];
    const float* Wt    = (const float*)d_in[2];
    const float* bt    = (const float*)d_in[3];
    const float* gt    = (const float*)d_in[4];
    const float* bbt   = (const float*)d_in[5];
    const float* W1    = (const float*)d_in[6];
    const float* W2    = (const float*)d_in[7];
    const float* gamma = (const float*)d_in[8];
    const float* beta  = (const float*)d_in[9];
    float* out = (float*)d_out;

    char* ws = (char*)d_ws;
    unsigned* hB    = (unsigned*)(ws + WS_HB);
    unsigned* aggB  = (unsigned*)(ws + WS_AGG);
    float*    stats = (float*)(ws + WS_STATS);   // 4 stage buffers of NCOPY*128
    int*      deg   = (int*)(ws + WS_DEG);
    int*      offs  = (int*)(ws + WS_OFFS);
    int*      cur   = (int*)(ws + WS_CUR);
    int*      parts = (int*)(ws + WS_PARTS);
    int*      esrc  = (int*)(ws + WS_ESRC);

    float* st0 = stats;
    float* st1 = stats + NCOPY * 128;
    float* st2 = stats + 2 * NCOPY * 128;
    float* st3 = stats + 3 * NCOPY * 128;

    const int* srcv = ei;
    const int* dstv = ei + NED;

    // one memset covers all 4 stat buffers + deg (contiguous)
    hipMemsetAsync(stats, 0, 4 * NCOPY * 128 * 4 + NND * 4, stream);

    const int PGRID = FCH * 8;   // 1568 blocks: 8 XCD slices x 196 edge chunks
    k_deg<<<PGRID, 256, 0, stream>>>(dstv, deg);
    k_part<<<NSB, SCB, 0, stream>>>(deg, offs, parts);
    k_scan2<<<1, 256, 0, stream>>>(parts);
    k_apply<<<NSB, 256, 0, stream>>>(offs, parts, cur);
    k_fill<<<PGRID, 256, 0, stream>>>(srcv, dstv, cur, esrc);

    const int NT = 782;             // one 64-node tile per block
    const int NB = NND / 4;         // 12500 agg blocks

    k_transform<<<NT, 128, 0, stream>>>(x, Wt, bt, hB, st0);

    // layer 0: BN(st0; g_t) folded into agg
    k_agg<<<NB, 256, 0, stream>>>((const uint4*)hB, (uint4*)aggB, st0, gt, bbt, offs, esrc);
    k_mlp<<<NT, 128, 0, stream>>>((const uint4*)aggB, nullptr, hB, st1, W1, W2);

    // layer 1: BN(st1; gamma[0]) folded into agg
    k_agg<<<NB, 256, 0, stream>>>((const uint4*)hB, (uint4*)aggB, st1, gamma, beta, offs, esrc);
    k_mlp<<<NT, 128, 0, stream>>>((const uint4*)aggB, nullptr, hB, st2, W1 + 4096, W2 + 4096);

    // layer 2: BN(st2; gamma[1]) folded into agg; f32 out for final BN
    k_agg<<<NB, 256, 0, stream>>>((const uint4*)hB, (uint4*)aggB, st2, gamma + 64, beta + 64, offs, esrc);
    k_mlp<<<NT, 128, 0, stream>>>((const uint4*)aggB, out, nullptr, st3, W1 + 8192, W2 + 8192);

    // final BN apply (BN(st3; gamma[2]) derived per block)
    k_bnout<<<(NND * NH / 4 + 255) / 256, 256, 0, stream>>>(out, st3, gamma + 128, beta + 128);
}

// Round 13
// 301.163 us; speedup vs baseline: 1.0736x; 1.0736x over previous
//
#include <hip/hip_runtime.h>

#define NND 50000
#define NED 800000
#define NF  128
#define NH  64
#define BN_EPS 1e-5
#define NCOPY 8    // stats slot-copies (f32)
#define SCB  256   // scan chunk
#define NSB  ((NND + SCB - 1) / SCB)   // 196 scan blocks
#define XNODES (NND / 8)               // 6250 nodes per XCD slice
#define FCH  196                       // edge chunks (1024 int4 each) per XCD pass
#define NT   782                       // transform/mlp tiles
#define PGRID (FCH * 8)                // 1568 edge-partition blocks

// ---- workspace byte offsets (16B aligned) ----
#define WS_HB     0                          // bf16[NND*64]  (h, gather source)   6,400,000 B
#define WS_AGG    6400000                    // bf16[NND*64]  (agg, MLP input)     6,400,000 B
#define WS_STATS  12800000                   // float[4][NCOPY*128] = 16 KB (4 stages, memset each call)
#define WS_DEG    (WS_STATS + 4*NCOPY*128*4) // int[NND]  (memset'd with stats)
#define WS_OFFS   (WS_DEG + NND*4)           // int[NND+4]
#define WS_CUR    (WS_OFFS + (NND+4)*4)      // int[NND]
#define WS_PARTS  (WS_CUR + NND*4)           // int[256]
#define WS_ESRC   (WS_PARTS + 256*4)         // int[NED]

// ---- bf16 helpers (storage-only; all math in f32) ----
__device__ __forceinline__ unsigned bfrn(float x) {          // f32 -> bf16 (RTN-even)
    unsigned u = __float_as_uint(x);
    return (u + 0x7fffu + ((u >> 16) & 1u)) >> 16;
}
__device__ __forceinline__ unsigned pk(float lo, float hi) { // 2x f32 -> packed bf16x2
    return bfrn(lo) | (bfrn(hi) << 16);
}
__device__ __forceinline__ void upadd(unsigned u, float& lo, float& hi) {
    lo += __uint_as_float(u << 16);
    hi += __uint_as_float(u & 0xffff0000u);
}
__device__ __forceinline__ float ulo(unsigned u) { return __uint_as_float(u << 16); }
__device__ __forceinline__ float uhi(unsigned u) { return __uint_as_float(u & 0xffff0000u); }

// derive BN scale/shift for column c from f32 slot-copy stats
__device__ __forceinline__ void bn_derive(const float* __restrict__ st, int c,
                                          const float* __restrict__ g,
                                          const float* __restrict__ b,
                                          float& sc, float& sh) {
    float sum = 0.f, ssq = 0.f;
#pragma unroll
    for (int cp = 0; cp < NCOPY; ++cp) {
        sum += st[cp * 128 + c];
        ssq += st[cp * 128 + 64 + c];
    }
    double mu  = (double)sum / (double)NND;
    double var = (double)ssq / (double)NND - mu * mu;
    if (var < 0.0) var = 0.0;
    double rs = 1.0 / sqrt(var + BN_EPS);
    double scd = (double)g[c] * rs;
    sc = (float)scd;
    sh = (float)((double)b[c] - mu * scd);
}

// ---------------- FUSED: transform (blocks [0,NT)) || degree count (blocks [NT,NT+PGRID)) ----
// transform and deg are data-independent; fusing overlaps transform's VALU work
// under deg's atomic/gather latency. LDS 33.4KB -> 4 blocks/CU = 16 waves/CU,
// matching deg/fill's measured standalone occupancy (49%).
__global__ __launch_bounds__(256) void k_dtf(const int* __restrict__ dst,
                                             int* __restrict__ deg,
                                             const float* __restrict__ x,
                                             const float* __restrict__ Wt,
                                             const float* __restrict__ bt,
                                             unsigned* __restrict__ hB,
                                             float* __restrict__ stats) {
    __shared__ __align__(16) unsigned Wlu[NF * NH / 2]; // 16 KB, bf16-packed
    __shared__ __align__(16) float sT[64 * 68];         // 17.4 KB
    int tid = threadIdx.x;

    if (blockIdx.x >= NT) {
        // ---- degree-count body (XCD-partitioned, plain loads) ----
        int dbid = blockIdx.x - NT;
        int xcd = dbid & 7;
        int chunk = dbid >> 3;
        int lo = xcd * XNODES;
        const int4* d4 = (const int4*)dst;
#pragma unroll
        for (int r = 0; r < 4; ++r) {
            int i = chunk * 1024 + r * 256 + tid;
            if (i < NED / 4) {
                int4 d = d4[i];
                if ((unsigned)(d.x - lo) < XNODES) atomicAdd(&deg[d.x], 1);
                if ((unsigned)(d.y - lo) < XNODES) atomicAdd(&deg[d.y], 1);
                if ((unsigned)(d.z - lo) < XNODES) atomicAdd(&deg[d.z], 1);
                if ((unsigned)(d.w - lo) < XNODES) atomicAdd(&deg[d.w], 1);
            }
        }
        return;
    }

    // ---- transform body: one 64-node tile; all 256 threads stage, waves 0-1 compute ----
    int tile = blockIdx.x;
    int base = tile * 64;
    const float4* x4 = (const float4*)x;

    // stage W as bf16 pairs: 2048 uint2 by 256 threads
#pragma unroll
    for (int r = 0; r < 8; ++r) {
        int i4 = r * 256 + tid;
        float4 w = ((const float4*)Wt)[i4];
        uint2 wp; wp.x = pk(w.x, w.y); wp.y = pk(w.z, w.w);
        ((uint2*)Wlu)[i4] = wp;
    }

    int wave = tid >> 6, lane = tid & 63;
    int ti = lane & 7, tj = lane >> 3;
    int cw = wave * 32 + tj * 4;          // compute waves 0-1: output cols

    float acc[8][4];
#pragma unroll
    for (int i = 0; i < 8; ++i)
#pragma unroll
        for (int j = 0; j < 4; ++j) acc[i][j] = 0.f;

    for (int ch = 0; ch < 2; ++ch) {
        __syncthreads();
        // T14 split: issue all chunk loads to regs, then LDS stores (all 256 threads)
        float4 pf[4];
#pragma unroll
        for (int s = 0; s < 4; ++s) {
            int flat = s * 256 + tid;
            int nl = flat >> 4, q = flat & 15;
            pf[s] = make_float4(0.f, 0.f, 0.f, 0.f);
            if (base + nl < NND) pf[s] = x4[(size_t)(base + nl) * 32 + ch * 16 + q];
        }
#pragma unroll
        for (int s = 0; s < 4; ++s) {
            int flat = s * 256 + tid;
            int nl = flat >> 4, q = flat & 15;
            sT[(q * 4 + 0) * 68 + nl] = pf[s].x;
            sT[(q * 4 + 1) * 68 + nl] = pf[s].y;
            sT[(q * 4 + 2) * 68 + nl] = pf[s].z;
            sT[(q * 4 + 3) * 68 + nl] = pf[s].w;
        }
        __syncthreads();
        if (tid < 128) {
#pragma unroll 4
            for (int k = 0; k < 64; ++k) {
                const float* ap = &sT[k * 68 + ti * 8];
                float4 alo = *(const float4*)ap;
                float4 ahi = *(const float4*)(ap + 4);
                uint2 wu = *(const uint2*)&Wlu[(ch * 64 + k) * 32 + (cw >> 1)];
                float a8[8] = {alo.x, alo.y, alo.z, alo.w, ahi.x, ahi.y, ahi.z, ahi.w};
                float w4[4] = {ulo(wu.x), uhi(wu.x), ulo(wu.y), uhi(wu.y)};
#pragma unroll
                for (int i = 0; i < 8; ++i)
#pragma unroll
                    for (int j = 0; j < 4; ++j) acc[i][j] += a8[i] * w4[j];
            }
        }
    }
    if (tid >= 128) return;

    float4 bv = *(const float4*)&bt[cw];
    float bj[4] = {bv.x, bv.y, bv.z, bv.w};

    float s4[4] = {0.f, 0.f, 0.f, 0.f}, q4[4] = {0.f, 0.f, 0.f, 0.f};
    uint2* hB2 = (uint2*)hB;
#pragma unroll
    for (int i = 0; i < 8; ++i) {
        int n = base + ti * 8 + i;
        if (n < NND) {
            float o[4];
#pragma unroll
            for (int j = 0; j < 4; ++j) {
                o[j] = acc[i][j] + bj[j];
                s4[j] += o[j];
                q4[j] += o[j] * o[j];
            }
            uint2 ov; ov.x = pk(o[0], o[1]); ov.y = pk(o[2], o[3]);
            hB2[(size_t)n * 16 + wave * 8 + tj] = ov;
        }
    }
#pragma unroll
    for (int m = 1; m < 8; m <<= 1) {
#pragma unroll
        for (int j = 0; j < 4; ++j) {
            s4[j] += __shfl_xor(s4[j], m);
            q4[j] += __shfl_xor(q4[j], m);
        }
    }
    if (ti == 0) {
        int slot = (tile & (NCOPY - 1)) * 128;
#pragma unroll
        for (int j = 0; j < 4; ++j) {
            atomicAdd(&stats[slot + cw + j], s4[j]);
            atomicAdd(&stats[slot + 64 + cw + j], q4[j]);
        }
    }
}

// ---------------- CSR fill (XCD-partitioned, plain loads — nt reverted, R12 evidence) ----------------
__global__ __launch_bounds__(256) void k_fill(const int* __restrict__ src,
                                              const int* __restrict__ dst,
                                              int* __restrict__ cur,
                                              int* __restrict__ esrc) {
    int xcd = blockIdx.x & 7;
    int chunk = blockIdx.x >> 3;
    int lo = xcd * XNODES;
    const int4* d4 = (const int4*)dst;
    const int4* s4 = (const int4*)src;
#pragma unroll
    for (int r = 0; r < 4; ++r) {
        int i = chunk * 1024 + r * 256 + threadIdx.x;
        if (i < NED / 4) {
            int4 d = d4[i];
            int4 s = s4[i];
            if ((unsigned)(d.x - lo) < XNODES) esrc[atomicAdd(&cur[d.x], 1)] = s.x;
            if ((unsigned)(d.y - lo) < XNODES) esrc[atomicAdd(&cur[d.y], 1)] = s.y;
            if ((unsigned)(d.z - lo) < XNODES) esrc[atomicAdd(&cur[d.z], 1)] = s.z;
            if ((unsigned)(d.w - lo) < XNODES) esrc[atomicAdd(&cur[d.w], 1)] = s.w;
        }
    }
}

__global__ __launch_bounds__(SCB) void k_part(const int* __restrict__ deg,
                                              int* __restrict__ offs,
                                              int* __restrict__ parts) {
    __shared__ int sd[SCB];
    int t = threadIdx.x;
    int i = blockIdx.x * SCB + t;
    int v = (i < NND) ? deg[i] : 0;
    sd[t] = v;
    __syncthreads();
#pragma unroll
    for (int off = 1; off < SCB; off <<= 1) {
        int u = (t >= off) ? sd[t - off] : 0;
        __syncthreads();
        sd[t] += u;
        __syncthreads();
    }
    if (i < NND) offs[i] = sd[t] - v;
    if (t == SCB - 1) parts[blockIdx.x] = sd[t];
}

__global__ __launch_bounds__(256) void k_scan2(int* __restrict__ parts) {
    __shared__ int sd[256];
    int t = threadIdx.x;
    int v = (t < NSB) ? parts[t] : 0;
    sd[t] = v;
    __syncthreads();
#pragma unroll
    for (int off = 1; off < 256; off <<= 1) {
        int u = (t >= off) ? sd[t - off] : 0;
        __syncthreads();
        sd[t] += u;
        __syncthreads();
    }
    if (t < NSB) parts[t] = sd[t] - v;
}

__global__ __launch_bounds__(256) void k_apply(int* __restrict__ offs,
                                               const int* __restrict__ parts,
                                               int* __restrict__ cur) {
    int i = blockIdx.x * 256 + threadIdx.x;
    if (i < NND) {
        int o = offs[i] + parts[i >> 8];
        offs[i] = o;
        cur[i] = o;
    }
    if (i == NND) offs[NND] = NED;
}

// ---------------- aggregation: wave-per-node, bf16 rows; BN derived inline ----------------
__global__ __launch_bounds__(256) void k_agg(const uint4* __restrict__ hB4,
                                             uint4* __restrict__ aggB4,
                                             const float* __restrict__ stats,
                                             const float* __restrict__ g,
                                             const float* __restrict__ b,
                                             const int* __restrict__ offs,
                                             const int* __restrict__ esrc) {
    int tid  = threadIdx.x;
    int lane = tid & 63;
    int wv   = tid >> 6;
    int n = blockIdx.x * 4 + wv;
    int q = lane & 7;        // 16B sub-block within 128B row
    int r = lane >> 3;       // edge slot 0..7

    // per-lane BN derive for column `lane` (redundant across waves; L2-hot 4KB)
    float scl, shl;
    bn_derive(stats, lane, g, b, scl, shl);

    int e0 = offs[n], e1 = offs[n + 1];
    int deg = e1 - e0;

    float a[8];
#pragma unroll
    for (int i = 0; i < 8; ++i) a[i] = 0.f;

    if (r == 0) {
        uint4 u = hB4[(size_t)n * 8 + q];
        upadd(u.x, a[0], a[1]); upadd(u.y, a[2], a[3]);
        upadd(u.z, a[4], a[5]); upadd(u.w, a[6], a[7]);
    }

    for (int bb = e0; bb < e1; bb += 64) {
        int m = e1 - bb; if (m > 64) m = 64;
        int idx = (lane < m) ? esrc[bb + lane] : 0;
        int t = 0;
        for (; t + 32 <= m; t += 32) {
            int j0 = __shfl(idx, t + r);
            int j1 = __shfl(idx, t + 8 + r);
            int j2 = __shfl(idx, t + 16 + r);
            int j3 = __shfl(idx, t + 24 + r);
            uint4 u0 = hB4[(size_t)j0 * 8 + q];
            uint4 u1 = hB4[(size_t)j1 * 8 + q];
            uint4 u2 = hB4[(size_t)j2 * 8 + q];
            uint4 u3 = hB4[(size_t)j3 * 8 + q];
            upadd(u0.x, a[0], a[1]); upadd(u0.y, a[2], a[3]);
            upadd(u0.z, a[4], a[5]); upadd(u0.w, a[6], a[7]);
            upadd(u1.x, a[0], a[1]); upadd(u1.y, a[2], a[3]);
            upadd(u1.z, a[4], a[5]); upadd(u1.w, a[6], a[7]);
            upadd(u2.x, a[0], a[1]); upadd(u2.y, a[2], a[3]);
            upadd(u2.z, a[4], a[5]); upadd(u2.w, a[6], a[7]);
            upadd(u3.x, a[0], a[1]); upadd(u3.y, a[2], a[3]);
            upadd(u3.z, a[4], a[5]); upadd(u3.w, a[6], a[7]);
        }
        for (; t < m; t += 8) {
            int e = t + r;
            int j = __shfl(idx, e & 63);
            if (e < m) {
                uint4 u = hB4[(size_t)j * 8 + q];
                upadd(u.x, a[0], a[1]); upadd(u.y, a[2], a[3]);
                upadd(u.z, a[4], a[5]); upadd(u.w, a[6], a[7]);
            }
        }
    }

#pragma unroll
    for (int msk = 8; msk <= 32; msk <<= 1)
#pragma unroll
        for (int i = 0; i < 8; ++i) a[i] += __shfl_xor(a[i], msk);

    // gather the 8 (sc,sh) pairs for this lane's columns q*8..q*8+7
    float sc8[8], sh8[8];
#pragma unroll
    for (int j = 0; j < 8; ++j) {
        sc8[j] = __shfl(scl, q * 8 + j);
        sh8[j] = __shfl(shl, q * 8 + j);
    }

    if (r == 0) {
        float dn = (float)(deg + 1);
        float o[8];
#pragma unroll
        for (int j = 0; j < 8; ++j) o[j] = sc8[j] * a[j] + dn * sh8[j];
        uint4 ov;
        ov.x = pk(o[0], o[1]); ov.y = pk(o[2], o[3]);
        ov.z = pk(o[4], o[5]); ov.w = pk(o[6], o[7]);
        aggB4[(size_t)n * 8 + q] = ov;
    }
}

// ---------------- MLP: col-split 1-tile blocks (2 waves, acc 8x4), 2 GEMMs ----------------
__global__ __launch_bounds__(128) void k_mlp(const uint4* __restrict__ aggB4,
                                             float* __restrict__ outF,    // f32 out (last layer) or null
                                             unsigned* __restrict__ hBo,  // bf16 out or null
                                             float* __restrict__ stats,
                                             const float* __restrict__ W1,
                                             const float* __restrict__ W2) {
    __shared__ __align__(16) float W1l[NH * NH];  // 16 KB
    __shared__ __align__(16) float W2l[NH * NH];  // 16 KB
    __shared__ __align__(16) float sT[64 * 68];   // 17.4 KB (agg, then t1)
    int tid  = threadIdx.x;
    int wave = tid >> 6, lane = tid & 63;
    int ti = lane & 7, tj = lane >> 3;
    int tile = blockIdx.x;
    int base = tile * 64;
    int cw = wave * 32 + tj * 4;

#pragma unroll
    for (int r = 0; r < 8; ++r) {
        int i4 = r * 128 + tid;
        ((float4*)W1l)[i4] = ((const float4*)W1)[i4];
        ((float4*)W2l)[i4] = ((const float4*)W2)[i4];
    }
    // stage agg tile transposed (bf16 -> f32): 512 uint4 by 128 threads
#pragma unroll
    for (int s = 0; s < 4; ++s) {
        int i4 = s * 128 + tid;
        int nl = i4 >> 3, q = i4 & 7;
        uint4 u = make_uint4(0u, 0u, 0u, 0u);
        if (base + nl < NND) u = aggB4[(size_t)(base + nl) * 8 + q];
        sT[(q * 8 + 0) * 68 + nl] = ulo(u.x);
        sT[(q * 8 + 1) * 68 + nl] = uhi(u.x);
        sT[(q * 8 + 2) * 68 + nl] = ulo(u.y);
        sT[(q * 8 + 3) * 68 + nl] = uhi(u.y);
        sT[(q * 8 + 4) * 68 + nl] = ulo(u.z);
        sT[(q * 8 + 5) * 68 + nl] = uhi(u.z);
        sT[(q * 8 + 6) * 68 + nl] = ulo(u.w);
        sT[(q * 8 + 7) * 68 + nl] = uhi(u.w);
    }
    __syncthreads();

    // GEMM1: t1[:, cw..cw+3] = relu(agg @ W1)
    float a1[8][4];
#pragma unroll
    for (int i = 0; i < 8; ++i)
#pragma unroll
        for (int j = 0; j < 4; ++j) a1[i][j] = 0.f;
#pragma unroll 4
    for (int k = 0; k < 64; ++k) {
        const float* ap = &sT[k * 68 + ti * 8];
        float4 alo = *(const float4*)ap;
        float4 ahi = *(const float4*)(ap + 4);
        float4 wv  = *(const float4*)&W1l[k * NH + cw];
        float a8[8] = {alo.x, alo.y, alo.z, alo.w, ahi.x, ahi.y, ahi.z, ahi.w};
        float w4[4] = {wv.x, wv.y, wv.z, wv.w};
#pragma unroll
        for (int i = 0; i < 8; ++i)
#pragma unroll
            for (int j = 0; j < 4; ++j) a1[i][j] += a8[i] * w4[j];
    }
#pragma unroll
    for (int i = 0; i < 8; ++i)
#pragma unroll
        for (int j = 0; j < 4; ++j) a1[i][j] = fmaxf(a1[i][j], 0.f);

    __syncthreads();
#pragma unroll
    for (int j = 0; j < 4; ++j) {
        float* p = &sT[(cw + j) * 68 + ti * 8];
        float4 lo = {a1[0][j], a1[1][j], a1[2][j], a1[3][j]};
        float4 hi = {a1[4][j], a1[5][j], a1[6][j], a1[7][j]};
        *(float4*)p = lo;
        *(float4*)(p + 4) = hi;
    }
    __syncthreads();

    // GEMM2: out[:, cw..cw+3] = relu(t1 @ W2)
    float a2[8][4];
#pragma unroll
    for (int i = 0; i < 8; ++i)
#pragma unroll
        for (int j = 0; j < 4; ++j) a2[i][j] = 0.f;
#pragma unroll 4
    for (int k = 0; k < 64; ++k) {
        const float* ap = &sT[k * 68 + ti * 8];
        float4 alo = *(const float4*)ap;
        float4 ahi = *(const float4*)(ap + 4);
        float4 wv  = *(const float4*)&W2l[k * NH + cw];
        float a8[8] = {alo.x, alo.y, alo.z, alo.w, ahi.x, ahi.y, ahi.z, ahi.w};
        float w4[4] = {wv.x, wv.y, wv.z, wv.w};
#pragma unroll
        for (int i = 0; i < 8; ++i)
#pragma unroll
            for (int j = 0; j < 4; ++j) a2[i][j] += a8[i] * w4[j];
    }

    float s4[4] = {0.f, 0.f, 0.f, 0.f}, q4[4] = {0.f, 0.f, 0.f, 0.f};
    uint2* hBo2 = (uint2*)hBo;
#pragma unroll
    for (int i = 0; i < 8; ++i) {
        int n = base + ti * 8 + i;
        if (n < NND) {
            float o[4];
#pragma unroll
            for (int j = 0; j < 4; ++j) {
                o[j] = fmaxf(a2[i][j], 0.f);
                s4[j] += o[j];
                q4[j] += o[j] * o[j];
            }
            if (outF) *(float4*)&outF[(size_t)n * NH + cw] = *(float4*)&o[0];
            if (hBo) {
                uint2 ov; ov.x = pk(o[0], o[1]); ov.y = pk(o[2], o[3]);
                hBo2[(size_t)n * 16 + wave * 8 + tj] = ov;
            }
        }
    }
#pragma unroll
    for (int m = 1; m < 8; m <<= 1) {
#pragma unroll
        for (int j = 0; j < 4; ++j) {
            s4[j] += __shfl_xor(s4[j], m);
            q4[j] += __shfl_xor(q4[j], m);
        }
    }
    if (ti == 0) {
        int slot = (tile & (NCOPY - 1)) * 128;
#pragma unroll
        for (int j = 0; j < 4; ++j) {
            atomicAdd(&stats[slot + cw + j], s4[j]);
            atomicAdd(&stats[slot + 64 + cw + j], q4[j]);
        }
    }
}

// ---------------- final BN apply, in-place on f32 out; sc/sh derived per block ----------------
__global__ __launch_bounds__(256) void k_bnout(float* __restrict__ h,
                                               const float* __restrict__ stats,
                                               const float* __restrict__ g,
                                               const float* __restrict__ b) {
    __shared__ float sl[128];
    int tid = threadIdx.x;
    if (tid < 64) {
        float sc, sh;
        bn_derive(stats, tid, g, b, sc, sh);
        sl[tid]      = sc;
        sl[64 + tid] = sh;
    }
    __syncthreads();
    int i4 = blockIdx.x * 256 + tid;
    if (i4 < NND * NH / 4) {
        int cg = i4 & 15;
        float4 v   = ((float4*)h)[i4];
        float4 scv = *(float4*)&sl[cg * 4];
        float4 shv = *(float4*)&sl[64 + cg * 4];
        v.x = v.x * scv.x + shv.x;
        v.y = v.y * scv.y + shv.y;
        v.z = v.z * scv.z + shv.z;
        v.w = v.w * scv.w + shv.w;
        ((float4*)h)[i4] = v;
    }
}

extern "C" void kernel_launch(void* const* d_in, const int* in_sizes, int n_in,
                              void* d_out, int out_size, void* d_ws, size_t ws_size,
                              hipStream_t stream) {
    const float* x     = (const float*)d_in[0];
    const int*   ei    = (const int*)d_in[1];
    const float* Wt    = (const float*)d_in[2];
    const float* bt    = (const float*)d_in[3];
    const float* gt    = (const float*)d_in[4];
    const float* bbt   = (const float*)d_in[5];
    const float* W1    = (const float*)d_in[6];
    const float* W2    = (const float*)d_in[7];
    const float* gamma = (const float*)d_in[8];
    const float* beta  = (const float*)d_in[9];
    float* out = (float*)d_out;

    char* ws = (char*)d_ws;
    unsigned* hB    = (unsigned*)(ws + WS_HB);
    unsigned* aggB  = (unsigned*)(ws + WS_AGG);
    float*    stats = (float*)(ws + WS_STATS);   // 4 stage buffers of NCOPY*128
    int*      deg   = (int*)(ws + WS_DEG);
    int*      offs  = (int*)(ws + WS_OFFS);
    int*      cur   = (int*)(ws + WS_CUR);
    int*      parts = (int*)(ws + WS_PARTS);
    int*      esrc  = (int*)(ws + WS_ESRC);

    float* st0 = stats;
    float* st1 = stats + NCOPY * 128;
    float* st2 = stats + 2 * NCOPY * 128;
    float* st3 = stats + 3 * NCOPY * 128;

    const int* srcv = ei;
    const int* dstv = ei + NED;

    // one memset covers all 4 stat buffers + deg (contiguous)
    hipMemsetAsync(stats, 0, 4 * NCOPY * 128 * 4 + NND * 4, stream);

    // fused transform || degree count
    k_dtf<<<NT + PGRID, 256, 0, stream>>>(dstv, deg, x, Wt, bt, hB, st0);
    k_part<<<NSB, SCB, 0, stream>>>(deg, offs, parts);
    k_scan2<<<1, 256, 0, stream>>>(parts);
    k_apply<<<NSB, 256, 0, stream>>>(offs, parts, cur);
    k_fill<<<PGRID, 256, 0, stream>>>(srcv, dstv, cur, esrc);

    const int NB = NND / 4;         // 12500 agg blocks

    // layer 0: BN(st0; g_t) folded into agg
    k_agg<<<NB, 256, 0, stream>>>((const uint4*)hB, (uint4*)aggB, st0, gt, bbt, offs, esrc);
    k_mlp<<<NT, 128, 0, stream>>>((const uint4*)aggB, nullptr, hB, st1, W1, W2);

    // layer 1: BN(st1; gamma[0]) folded into agg
    k_agg<<<NB, 256, 0, stream>>>((const uint4*)hB, (uint4*)aggB, st1, gamma, beta, offs, esrc);
    k_mlp<<<NT, 128, 0, stream>>>((const uint4*)aggB, nullptr, hB, st2, W1 + 4096, W2 + 4096);

    // layer 2: BN(st2; gamma[1]) folded into agg; f32 out for final BN
    k_agg<<<NB, 256, 0, stream>>>((const uint4*)hB, (uint4*)aggB, st2, gamma + 64, beta + 64, offs, esrc);
    k_mlp<<<NT, 128, 0, stream>>>((const uint4*)aggB, out, nullptr, st3, W1 + 8192, W2 + 8192);

    // final BN apply (BN(st3; gamma[2]) derived per block)
    k_bnout<<<(NND * NH / 4 + 255) / 256, 256, 0, stream>>>(out, st3, gamma + 128, beta + 128);
}